// Round 1
// baseline (337.955 us; speedup 1.0000x reference)
//
#include <hip/hip_runtime.h>
#include <hip/hip_bf16.h>

#define NB 8
#define NC 256
#define NT 16384

using bf16x8 = __attribute__((ext_vector_type(8))) __bf16;
using f32x16 = __attribute__((ext_vector_type(16))) float;
using f32x4  = __attribute__((ext_vector_type(4))) float;
using u32x4  = __attribute__((ext_vector_type(4))) unsigned int;

// Pack two fp32 -> two bf16 (truncation) in one v_perm_b32.
// low short = bf16(f_lo), high short = bf16(f_hi)
__device__ __forceinline__ unsigned int pack_bf16_pair(float f_lo, float f_hi) {
  unsigned int ulo = __float_as_uint(f_lo), uhi = __float_as_uint(f_hi);
  return __builtin_amdgcn_perm(uhi, ulo, 0x07060302u);
}

__device__ __forceinline__ unsigned short bf16_rne(float f) {
  unsigned int u = __float_as_uint(f);
  u += 0x7FFFu + ((u >> 16) & 1u);
  return (unsigned short)(u >> 16);
}

// ---------------------------------------------------------------------------
// K1: G[b] += X_chunk * X_chunk^T   (X = x[b], 256 x 16384, split-K over 32
// chunks of 512, one 1024-thread wg computes the full 256x256 tile so the
// LDS slab serves both MFMA operands; fp32 atomicAdd merge into ws)
// ---------------------------------------------------------------------------
__global__ __launch_bounds__(1024) void k_gram(const float* __restrict__ x,
                                               float* __restrict__ G) {
  // stride 72 shorts = 144 B: rows 16B-aligned (ds_read_b128 legal),
  // 144/4 mod 32 = 4 -> bank-uniform for frag reads and staging writes
  __shared__ __align__(16) unsigned short lds[256 * 72];
  const int b   = blockIdx.y;
  const int kc  = blockIdx.x;            // 32 chunks of K=512
  const int tid = threadIdx.x;
  const int l   = tid & 63, w = tid >> 6; // 16 waves, 4x4 grid of 64x64 wave tiles
  const int wr  = w >> 2, wc = w & 3;
  const int l31 = l & 31, lh = l >> 5;

  const float* __restrict__ xb = x + (size_t)b * NC * NT;

  // staging: thread -> (row, 16-float quarter) of the 256x64 slab
  const int sr = tid >> 2;
  const int sq = tid & 3;
  const float* sp = xb + (size_t)sr * NT + kc * 512 + sq * 16;

  f32x4 r0 = ((const f32x4*)sp)[0];
  f32x4 r1 = ((const f32x4*)sp)[1];
  f32x4 r2 = ((const f32x4*)sp)[2];
  f32x4 r3 = ((const f32x4*)sp)[3];

  f32x16 acc00, acc01, acc10, acc11;
#pragma unroll
  for (int i = 0; i < 16; ++i) { acc00[i] = 0.f; acc01[i] = 0.f; acc10[i] = 0.f; acc11[i] = 0.f; }

#pragma unroll 1
  for (int it = 0; it < 8; ++it) {       // 8 iters of BK=64
    __syncthreads();
    u32x4 p0, p1;
    p0[0] = pack_bf16_pair(r0[0], r0[1]); p0[1] = pack_bf16_pair(r0[2], r0[3]);
    p0[2] = pack_bf16_pair(r1[0], r1[1]); p0[3] = pack_bf16_pair(r1[2], r1[3]);
    p1[0] = pack_bf16_pair(r2[0], r2[1]); p1[1] = pack_bf16_pair(r2[2], r2[3]);
    p1[2] = pack_bf16_pair(r3[0], r3[1]); p1[3] = pack_bf16_pair(r3[2], r3[3]);
    u32x4* dst = (u32x4*)&lds[sr * 72 + sq * 16];
    dst[0] = p0;
    dst[1] = p1;
    if (it < 7) {                        // prefetch next slab into regs (overlaps MFMA)
      const float* np = sp + (it + 1) * 64;
      r0 = ((const f32x4*)np)[0]; r1 = ((const f32x4*)np)[1];
      r2 = ((const f32x4*)np)[2]; r3 = ((const f32x4*)np)[3];
    }
    __syncthreads();
#pragma unroll
    for (int s = 0; s < 4; ++s) {        // 4 ksteps of 16
      const int ko = s * 16 + lh * 8;
      bf16x8 a0 = *(const bf16x8*)&lds[(wr * 64 +      l31) * 72 + ko];
      bf16x8 a1 = *(const bf16x8*)&lds[(wr * 64 + 32 + l31) * 72 + ko];
      bf16x8 b0 = *(const bf16x8*)&lds[(wc * 64 +      l31) * 72 + ko];
      bf16x8 b1 = *(const bf16x8*)&lds[(wc * 64 + 32 + l31) * 72 + ko];
      acc00 = __builtin_amdgcn_mfma_f32_32x32x16_bf16(a0, b0, acc00, 0, 0, 0);
      acc01 = __builtin_amdgcn_mfma_f32_32x32x16_bf16(a0, b1, acc01, 0, 0, 0);
      acc10 = __builtin_amdgcn_mfma_f32_32x32x16_bf16(a1, b0, acc10, 0, 0, 0);
      acc11 = __builtin_amdgcn_mfma_f32_32x32x16_bf16(a1, b1, acc11, 0, 0, 0);
    }
  }

  // C/D layout (m74/m101): col = lane&31, row = (reg&3) + 8*(reg>>2) + 4*(lane>>5)
  float* __restrict__ Gb = G + (size_t)b * NC * NC;
  const int ibase = wr * 64 + 4 * lh;
  const int jbase = wc * 64 + l31;
#pragma unroll
  for (int g = 0; g < 16; ++g) {
    const int ir = (g & 3) + 8 * (g >> 2);
    atomicAdd(&Gb[(ibase + ir) * NC      + jbase     ], acc00[g]);
    atomicAdd(&Gb[(ibase + ir) * NC      + jbase + 32], acc01[g]);
    atomicAdd(&Gb[(ibase + 32 + ir) * NC + jbase     ], acc10[g]);
    atomicAdd(&Gb[(ibase + 32 + ir) * NC + jbase + 32], acc11[g]);
  }
}

// ---------------------------------------------------------------------------
// K2: Att[row] = gamma * softmax(rowmax - G[row]) = gamma * exp(rowmin - G)/sum
// one wave per 256-wide row; gamma folded in so K3's epilogue is out + x.
// ---------------------------------------------------------------------------
__global__ __launch_bounds__(256) void k_softmax(const float* __restrict__ G,
                                                 const float* __restrict__ gamma,
                                                 unsigned short* __restrict__ Att) {
  const int row = blockIdx.x * 4 + (threadIdx.x >> 6);
  const int l   = threadIdx.x & 63;
  const float* __restrict__ g = G + (size_t)row * NC;
  float v0 = g[l], v1 = g[l + 64], v2 = g[l + 128], v3 = g[l + 192];
  float mn = fminf(fminf(v0, v1), fminf(v2, v3));
#pragma unroll
  for (int m = 32; m >= 1; m >>= 1) mn = fminf(mn, __shfl_xor(mn, m, 64));
  float p0 = __expf(mn - v0), p1 = __expf(mn - v1);
  float p2 = __expf(mn - v2), p3 = __expf(mn - v3);
  float s = (p0 + p1) + (p2 + p3);
#pragma unroll
  for (int m = 32; m >= 1; m >>= 1) s += __shfl_xor(s, m, 64);
  const float sc = gamma[0] / s;         // s >= 1 always (argmin term is 1)
  unsigned short* __restrict__ a = Att + (size_t)row * NC;
  a[l      ] = bf16_rne(p0 * sc);
  a[l +  64] = bf16_rne(p1 * sc);
  a[l + 128] = bf16_rne(p2 * sc);
  a[l + 192] = bf16_rne(p3 * sc);
}

// ---------------------------------------------------------------------------
// K3: y[b] = Att[b](256x256 bf16) * X[b] + x[b].  Per wg: 256 x 256(t) tile,
// K=256 streamed in BK=32.  B-slab kept fp32 [k][t] (+4 pad -> the transposed
// fragment gather is 8 conflict-free ds_read_b32); Att chunk staged bf16.
// 16 waves = 2(row) x 8(col); wave = 4 row-tiles x 1 col-tile (B-frag reuse x4).
// ---------------------------------------------------------------------------
__global__ __launch_bounds__(1024) void k_out(const float* __restrict__ x,
                                              const unsigned short* __restrict__ Att,
                                              float* __restrict__ y) {
  __shared__ __align__(16) float bs[32 * 260];           // 33280 B
  __shared__ __align__(16) unsigned short as_[256 * 40]; // 20480 B
  const int b   = blockIdx.y;
  const int t0  = blockIdx.x * 256;
  const int tid = threadIdx.x;
  const int l   = tid & 63, w = tid >> 6;
  const int rbw = w >> 3, cbw = w & 7;
  const int l31 = l & 31, lh = l >> 5;

  const float* __restrict__ xb = x + (size_t)b * NC * NT;
  const unsigned short* __restrict__ Ab = Att + (size_t)b * NC * NC;

  const int bk = tid >> 5, bf = tid & 31;   // B staging: (k row, float4 col)
  const int ar = tid >> 2, aseg = tid & 3;  // A staging: (i row, 8-short seg)

  const float* bsp = xb + (size_t)bk * NT + t0 + bf * 4;
  f32x4 rb0 = *(const f32x4*)bsp;
  f32x4 rb1 = *(const f32x4*)(bsp + 128);
  u32x4 ra  = *(const u32x4*)(Ab + ar * NC + aseg * 8);

  f32x16 acc0, acc1, acc2, acc3;
#pragma unroll
  for (int i = 0; i < 16; ++i) { acc0[i] = 0.f; acc1[i] = 0.f; acc2[i] = 0.f; acc3[i] = 0.f; }

#pragma unroll 1
  for (int it = 0; it < 8; ++it) {          // 8 iters of BK=32 over K=256
    __syncthreads();
    *(f32x4*)&bs[bk * 260 + bf * 4]       = rb0;
    *(f32x4*)&bs[bk * 260 + 128 + bf * 4] = rb1;
    *(u32x4*)&as_[ar * 40 + aseg * 8]     = ra;
    if (it < 7) {
      const float* np = bsp + (size_t)(it + 1) * 32 * NT;
      rb0 = *(const f32x4*)np;
      rb1 = *(const f32x4*)(np + 128);
      ra  = *(const u32x4*)(Ab + ar * NC + (it + 1) * 32 + aseg * 8);
    }
    __syncthreads();
#pragma unroll
    for (int s = 0; s < 2; ++s) {
      const int kr = s * 16 + lh * 8;
      const int tc = cbw * 32 + l31;
      // transposed B fragment: 8 strided fp32 reads, banks = (4k + t) % 32 -> conflict-free
      float f0 = bs[(kr + 0) * 260 + tc], f1 = bs[(kr + 1) * 260 + tc];
      float f2 = bs[(kr + 2) * 260 + tc], f3 = bs[(kr + 3) * 260 + tc];
      float f4 = bs[(kr + 4) * 260 + tc], f5 = bs[(kr + 5) * 260 + tc];
      float f6 = bs[(kr + 6) * 260 + tc], f7 = bs[(kr + 7) * 260 + tc];
      u32x4 pk;
      pk[0] = pack_bf16_pair(f0, f1); pk[1] = pack_bf16_pair(f2, f3);
      pk[2] = pack_bf16_pair(f4, f5); pk[3] = pack_bf16_pair(f6, f7);
      bf16x8 bfrag = __builtin_bit_cast(bf16x8, pk);
      const int ao = s * 16 + lh * 8;
      bf16x8 a0 = *(const bf16x8*)&as_[(rbw * 128 +      l31) * 40 + ao];
      bf16x8 a1 = *(const bf16x8*)&as_[(rbw * 128 + 32 + l31) * 40 + ao];
      bf16x8 a2 = *(const bf16x8*)&as_[(rbw * 128 + 64 + l31) * 40 + ao];
      bf16x8 a3 = *(const bf16x8*)&as_[(rbw * 128 + 96 + l31) * 40 + ao];
      acc0 = __builtin_amdgcn_mfma_f32_32x32x16_bf16(a0, bfrag, acc0, 0, 0, 0);
      acc1 = __builtin_amdgcn_mfma_f32_32x32x16_bf16(a1, bfrag, acc1, 0, 0, 0);
      acc2 = __builtin_amdgcn_mfma_f32_32x32x16_bf16(a2, bfrag, acc2, 0, 0, 0);
      acc3 = __builtin_amdgcn_mfma_f32_32x32x16_bf16(a3, bfrag, acc3, 0, 0, 0);
    }
  }

  // epilogue: y = out(+gamma already folded) + x, x re-read fp32 (L2-warm)
  const int tg = t0 + cbw * 32 + l31;
  const int ib = rbw * 128 + 4 * lh;
#pragma unroll
  for (int g = 0; g < 16; ++g) {
    const int ir = (g & 3) + 8 * (g >> 2);
    size_t i0 = (size_t)(b * NC + ib + ir) * NT + tg;
    y[i0] = acc0[g] + x[i0];
    size_t i1 = i0 + (size_t)32 * NT; y[i1] = acc1[g] + x[i1];
    size_t i2 = i0 + (size_t)64 * NT; y[i2] = acc2[g] + x[i2];
    size_t i3 = i0 + (size_t)96 * NT; y[i3] = acc3[g] + x[i3];
  }
}

extern "C" void kernel_launch(void* const* d_in, const int* in_sizes, int n_in,
                              void* d_out, int out_size, void* d_ws, size_t ws_size,
                              hipStream_t stream) {
  const float* x     = (const float*)d_in[0];
  const float* gamma = (const float*)d_in[1];
  float* y = (float*)d_out;

  // ws layout: G fp32 [8][256][256] (2 MiB) | Att bf16 [8][256][256] (1 MiB)
  float* G = (float*)d_ws;
  unsigned short* Att = (unsigned short*)((char*)d_ws + (size_t)NB * NC * NC * sizeof(float));

  hipMemsetAsync(G, 0, (size_t)NB * NC * NC * sizeof(float), stream);
  k_gram<<<dim3(32, NB), 1024, 0, stream>>>(x, G);
  k_softmax<<<dim3(NB * NC / 4), 256, 0, stream>>>(G, gamma, Att);
  k_out<<<dim3(NT / 256, NB), 1024, 0, stream>>>(x, Att, y);
}

// Round 2
// 282.980 us; speedup vs baseline: 1.1943x; 1.1943x over previous
//
#include <hip/hip_runtime.h>
#include <hip/hip_bf16.h>

#define NB 8
#define NC 256
#define NT 16384

using bf16x8 = __attribute__((ext_vector_type(8))) __bf16;
using f32x16 = __attribute__((ext_vector_type(16))) float;
using f32x4  = __attribute__((ext_vector_type(4))) float;
using u32x4  = __attribute__((ext_vector_type(4))) unsigned int;

__device__ __forceinline__ unsigned short bf16_rne(float f) {
  unsigned int u = __float_as_uint(f);
  u += 0x7FFFu + ((u >> 16) & 1u);
  return (unsigned short)(u >> 16);
}

// two fp32 -> packed bf16 pair, round-to-nearest-even
__device__ __forceinline__ unsigned int pack_bf16_pair_rne(float f_lo, float f_hi) {
  unsigned int a = __float_as_uint(f_lo), b = __float_as_uint(f_hi);
  a += 0x7FFFu + ((a >> 16) & 1u);
  b += 0x7FFFu + ((b >> 16) & 1u);
  return __builtin_amdgcn_perm(b, a, 0x07060302u);
}

// ---------------------------------------------------------------------------
// K1: Gp[kc][b] = X_chunk * X_chunk^T  (chunk = ITERS*64 of K=16384).
// One 1024-thread wg computes the full 256x256 tile (LDS slab serves both
// operands).  Plain streaming stores of the partial -- NO atomics (R1 showed
// 16.7M device-scope atomicAdds serialized at HBM: 100us, 6% MfmaUtil).
// ---------------------------------------------------------------------------
template <int ITERS>
__global__ __launch_bounds__(1024) void k_gram(const float* __restrict__ x,
                                               float* __restrict__ Gp) {
  // stride 72 shorts = 144 B: 16B-aligned rows, measured 0 bank conflicts (R1)
  __shared__ __align__(16) unsigned short lds[256 * 72];
  const int b   = blockIdx.y;
  const int kc  = blockIdx.x;
  const int tid = threadIdx.x;
  const int l   = tid & 63, w = tid >> 6; // 16 waves, 4x4 grid of 64x64 tiles
  const int wr  = w >> 2, wc = w & 3;
  const int l31 = l & 31, lh = l >> 5;

  const float* __restrict__ xb = x + (size_t)b * NC * NT;

  const int sr = tid >> 2;               // staging row
  const int sq = tid & 3;                // 16-float quarter
  const float* sp = xb + (size_t)sr * NT + kc * (ITERS * 64) + sq * 16;

  f32x4 r0 = ((const f32x4*)sp)[0];
  f32x4 r1 = ((const f32x4*)sp)[1];
  f32x4 r2 = ((const f32x4*)sp)[2];
  f32x4 r3 = ((const f32x4*)sp)[3];

  f32x16 acc00, acc01, acc10, acc11;
#pragma unroll
  for (int i = 0; i < 16; ++i) { acc00[i] = 0.f; acc01[i] = 0.f; acc10[i] = 0.f; acc11[i] = 0.f; }

#pragma unroll 1
  for (int it = 0; it < ITERS; ++it) {   // BK=64 per iter
    __syncthreads();
    u32x4 p0, p1;
    p0[0] = pack_bf16_pair_rne(r0[0], r0[1]); p0[1] = pack_bf16_pair_rne(r0[2], r0[3]);
    p0[2] = pack_bf16_pair_rne(r1[0], r1[1]); p0[3] = pack_bf16_pair_rne(r1[2], r1[3]);
    p1[0] = pack_bf16_pair_rne(r2[0], r2[1]); p1[1] = pack_bf16_pair_rne(r2[2], r2[3]);
    p1[2] = pack_bf16_pair_rne(r3[0], r3[1]); p1[3] = pack_bf16_pair_rne(r3[2], r3[3]);
    u32x4* dst = (u32x4*)&lds[sr * 72 + sq * 16];
    dst[0] = p0;
    dst[1] = p1;
    if (it < ITERS - 1) {                // prefetch next slab (overlaps MFMA)
      const float* np = sp + (it + 1) * 64;
      r0 = ((const f32x4*)np)[0]; r1 = ((const f32x4*)np)[1];
      r2 = ((const f32x4*)np)[2]; r3 = ((const f32x4*)np)[3];
    }
    __syncthreads();
#pragma unroll
    for (int s = 0; s < 4; ++s) {
      const int ko = s * 16 + lh * 8;
      bf16x8 a0 = *(const bf16x8*)&lds[(wr * 64 +      l31) * 72 + ko];
      bf16x8 a1 = *(const bf16x8*)&lds[(wr * 64 + 32 + l31) * 72 + ko];
      bf16x8 b0 = *(const bf16x8*)&lds[(wc * 64 +      l31) * 72 + ko];
      bf16x8 b1 = *(const bf16x8*)&lds[(wc * 64 + 32 + l31) * 72 + ko];
      acc00 = __builtin_amdgcn_mfma_f32_32x32x16_bf16(a0, b0, acc00, 0, 0, 0);
      acc01 = __builtin_amdgcn_mfma_f32_32x32x16_bf16(a0, b1, acc01, 0, 0, 0);
      acc10 = __builtin_amdgcn_mfma_f32_32x32x16_bf16(a1, b0, acc10, 0, 0, 0);
      acc11 = __builtin_amdgcn_mfma_f32_32x32x16_bf16(a1, b1, acc11, 0, 0, 0);
    }
  }

  // C/D layout (m74/m101): col = lane&31, row = (reg&3) + 8*(reg>>2) + 4*(lane>>5)
  float* __restrict__ Gb = Gp + ((size_t)kc * NB + b) * NC * NC;
  const int ibase = wr * 64 + 4 * lh;
  const int jbase = wc * 64 + l31;
#pragma unroll
  for (int g = 0; g < 16; ++g) {
    const int ir = (g & 3) + 8 * (g >> 2);
    Gb[(ibase + ir) * NC      + jbase     ] = acc00[g];
    Gb[(ibase + ir) * NC      + jbase + 32] = acc01[g];
    Gb[(ibase + 32 + ir) * NC + jbase     ] = acc10[g];
    Gb[(ibase + 32 + ir) * NC + jbase + 32] = acc11[g];
  }
}

// ---------------------------------------------------------------------------
// K2: reduce the NKC partials, then Att[row] = gamma*softmax(rowmin trick) + I.
// One wave per 256-wide row; identity folded in so K3 is a pure GEMM
// (y = (gamma*softmax + I) * X -- no epilogue x re-read).
// ---------------------------------------------------------------------------
template <int NKC>
__global__ __launch_bounds__(256) void k_softmax(const float* __restrict__ Gp,
                                                 const float* __restrict__ gamma,
                                                 unsigned short* __restrict__ Att) {
  const int row = blockIdx.x * 4 + (threadIdx.x >> 6); // global row 0..2047
  const int l   = threadIdx.x & 63;
  const int i   = row & (NC - 1);                      // channel index within batch
  const float* base = Gp + (size_t)row * NC + l * 4;

  f32x4 v; v[0] = 0.f; v[1] = 0.f; v[2] = 0.f; v[3] = 0.f;
#pragma unroll
  for (int kc = 0; kc < NKC; ++kc) {
    f32x4 p = *(const f32x4*)(base + (size_t)kc * (NB * NC * NC));
    v[0] += p[0]; v[1] += p[1]; v[2] += p[2]; v[3] += p[3];
  }

  float mn = fminf(fminf(v[0], v[1]), fminf(v[2], v[3]));
#pragma unroll
  for (int m = 32; m >= 1; m >>= 1) mn = fminf(mn, __shfl_xor(mn, m, 64));
  float p0 = __expf(mn - v[0]), p1 = __expf(mn - v[1]);
  float p2 = __expf(mn - v[2]), p3 = __expf(mn - v[3]);
  float s = (p0 + p1) + (p2 + p3);
#pragma unroll
  for (int m = 32; m >= 1; m >>= 1) s += __shfl_xor(s, m, 64);
  const float sc = gamma[0] / s;                       // s >= 1 (argmin term is 1)

  const int j0 = 4 * l;
  ushort4 o;
  o.x = bf16_rne(p0 * sc + ((j0 + 0) == i ? 1.f : 0.f));
  o.y = bf16_rne(p1 * sc + ((j0 + 1) == i ? 1.f : 0.f));
  o.z = bf16_rne(p2 * sc + ((j0 + 2) == i ? 1.f : 0.f));
  o.w = bf16_rne(p3 * sc + ((j0 + 3) == i ? 1.f : 0.f));
  *(ushort4*)(Att + (size_t)row * NC + j0) = o;
}

// ---------------------------------------------------------------------------
// K3: y[b] = Att'[b](256x256 bf16, I folded) * X[b].  Per wg: 256x256(t) tile,
// K=256 in BK=32.  B-slab fp32 [k][t] (+4 pad -> conflict-free transposed
// gather); Att chunk staged bf16.  Epilogue: pure store (residual is in Att').
// ---------------------------------------------------------------------------
__global__ __launch_bounds__(1024) void k_out(const float* __restrict__ x,
                                              const unsigned short* __restrict__ Att,
                                              float* __restrict__ y) {
  __shared__ __align__(16) float bs[32 * 260];           // 33280 B
  __shared__ __align__(16) unsigned short as_[256 * 40]; // 20480 B
  const int b   = blockIdx.y;
  const int t0  = blockIdx.x * 256;
  const int tid = threadIdx.x;
  const int l   = tid & 63, w = tid >> 6;
  const int rbw = w >> 3, cbw = w & 7;
  const int l31 = l & 31, lh = l >> 5;

  const float* __restrict__ xb = x + (size_t)b * NC * NT;
  const unsigned short* __restrict__ Ab = Att + (size_t)b * NC * NC;

  const int bk = tid >> 5, bf = tid & 31;   // B staging: (k row, float4 col)
  const int ar = tid >> 2, aseg = tid & 3;  // A staging: (i row, 8-short seg)

  const float* bsp = xb + (size_t)bk * NT + t0 + bf * 4;
  f32x4 rb0 = *(const f32x4*)bsp;
  f32x4 rb1 = *(const f32x4*)(bsp + 128);
  u32x4 ra  = *(const u32x4*)(Ab + ar * NC + aseg * 8);

  f32x16 acc0, acc1, acc2, acc3;
#pragma unroll
  for (int i = 0; i < 16; ++i) { acc0[i] = 0.f; acc1[i] = 0.f; acc2[i] = 0.f; acc3[i] = 0.f; }

#pragma unroll 1
  for (int it = 0; it < 8; ++it) {          // 8 iters of BK=32 over K=256
    __syncthreads();
    *(f32x4*)&bs[bk * 260 + bf * 4]       = rb0;
    *(f32x4*)&bs[bk * 260 + 128 + bf * 4] = rb1;
    *(u32x4*)&as_[ar * 40 + aseg * 8]     = ra;
    if (it < 7) {
      const float* np = bsp + (size_t)(it + 1) * 32 * NT;
      rb0 = *(const f32x4*)np;
      rb1 = *(const f32x4*)(np + 128);
      ra  = *(const u32x4*)(Ab + ar * NC + (it + 1) * 32 + aseg * 8);
    }
    __syncthreads();
#pragma unroll
    for (int s = 0; s < 2; ++s) {
      const int kr = s * 16 + lh * 8;
      const int tc = cbw * 32 + l31;
      // transposed B fragment: 8 strided fp32 reads, conflict-free banks
      float f0 = bs[(kr + 0) * 260 + tc], f1 = bs[(kr + 1) * 260 + tc];
      float f2 = bs[(kr + 2) * 260 + tc], f3 = bs[(kr + 3) * 260 + tc];
      float f4 = bs[(kr + 4) * 260 + tc], f5 = bs[(kr + 5) * 260 + tc];
      float f6 = bs[(kr + 6) * 260 + tc], f7 = bs[(kr + 7) * 260 + tc];
      u32x4 pk;
      pk[0] = pack_bf16_pair_rne(f0, f1); pk[1] = pack_bf16_pair_rne(f2, f3);
      pk[2] = pack_bf16_pair_rne(f4, f5); pk[3] = pack_bf16_pair_rne(f6, f7);
      bf16x8 bfrag = __builtin_bit_cast(bf16x8, pk);
      const int ao = s * 16 + lh * 8;
      bf16x8 a0 = *(const bf16x8*)&as_[(rbw * 128 +      l31) * 40 + ao];
      bf16x8 a1 = *(const bf16x8*)&as_[(rbw * 128 + 32 + l31) * 40 + ao];
      bf16x8 a2 = *(const bf16x8*)&as_[(rbw * 128 + 64 + l31) * 40 + ao];
      bf16x8 a3 = *(const bf16x8*)&as_[(rbw * 128 + 96 + l31) * 40 + ao];
      acc0 = __builtin_amdgcn_mfma_f32_32x32x16_bf16(a0, bfrag, acc0, 0, 0, 0);
      acc1 = __builtin_amdgcn_mfma_f32_32x32x16_bf16(a1, bfrag, acc1, 0, 0, 0);
      acc2 = __builtin_amdgcn_mfma_f32_32x32x16_bf16(a2, bfrag, acc2, 0, 0, 0);
      acc3 = __builtin_amdgcn_mfma_f32_32x32x16_bf16(a3, bfrag, acc3, 0, 0, 0);
    }
  }

  // epilogue: pure store (gamma and +x both folded into Att')
  const int tg = t0 + cbw * 32 + l31;
  const int ib = rbw * 128 + 4 * lh;
#pragma unroll
  for (int g = 0; g < 16; ++g) {
    const int ir = (g & 3) + 8 * (g >> 2);
    size_t i0 = (size_t)(b * NC + ib + ir) * NT + tg;
    y[i0] = acc0[g];
    y[i0 + (size_t)32 * NT] = acc1[g];
    y[i0 + (size_t)64 * NT] = acc2[g];
    y[i0 + (size_t)96 * NT] = acc3[g];
  }
}

extern "C" void kernel_launch(void* const* d_in, const int* in_sizes, int n_in,
                              void* d_out, int out_size, void* d_ws, size_t ws_size,
                              hipStream_t stream) {
  const float* x     = (const float*)d_in[0];
  const float* gamma = (const float*)d_in[1];
  float* y = (float*)d_out;

  // ws layout: Gp fp32 [NKC][8][256][256] | Att bf16 [8][256][256] (1 MiB)
  const size_t chunk_bytes = (size_t)NB * NC * NC * sizeof(float);  // 2 MiB
  const size_t att_bytes   = (size_t)NB * NC * NC * sizeof(unsigned short);

  // pick split-K width by available workspace (ws_size is call-invariant)
  int nkc;
  if      (ws_size >= 32 * chunk_bytes + att_bytes) nkc = 32;
  else if (ws_size >= 16 * chunk_bytes + att_bytes) nkc = 16;
  else if (ws_size >=  8 * chunk_bytes + att_bytes) nkc = 8;
  else                                              nkc = 4;

  float* Gp = (float*)d_ws;
  unsigned short* Att = (unsigned short*)((char*)d_ws + (size_t)nkc * chunk_bytes);

  switch (nkc) {
    case 32:
      k_gram<8>  <<<dim3(32, NB), 1024, 0, stream>>>(x, Gp);
      k_softmax<32><<<dim3(NB * NC / 4), 256, 0, stream>>>(Gp, gamma, Att);
      break;
    case 16:
      k_gram<16> <<<dim3(16, NB), 1024, 0, stream>>>(x, Gp);
      k_softmax<16><<<dim3(NB * NC / 4), 256, 0, stream>>>(Gp, gamma, Att);
      break;
    case 8:
      k_gram<32> <<<dim3(8, NB), 1024, 0, stream>>>(x, Gp);
      k_softmax<8><<<dim3(NB * NC / 4), 256, 0, stream>>>(Gp, gamma, Att);
      break;
    default:
      k_gram<64> <<<dim3(4, NB), 1024, 0, stream>>>(x, Gp);
      k_softmax<4><<<dim3(NB * NC / 4), 256, 0, stream>>>(Gp, gamma, Att);
      break;
  }
  k_out<<<dim3(NT / 256, NB), 1024, 0, stream>>>(x, Att, y);
}